// Round 2
// baseline (185.084 us; speedup 1.0000x reference)
//
#include <hip/hip_runtime.h>

// SparseDopplerAttention on gfx950 — R5.
// Identity (R3): out[q] = (sum_k P[q,k]*vsum[k]) / (sum_k P[q,k]),
//   vsum[k] = x[k] . colsum(Wv) + sum(bv)  (fp32) — V GEMM / PV GEMM eliminated.
// R4 post-mortem: launch_bounds(1024,8) + fully-unrolled weight loops => ~45
// dwords/thread scratch spill (WRITE_SIZE 90 MB). R5 keeps the 2-blocks/CU
// occupancy win but restructures for <=64 VGPR without spills:
//   - keys processed one 16-row half at a time (xk state 12 regs, not 24+12)
//   - #pragma unroll 1 on Q/K mtd loops and Phase-B t loop (no 4-deep weight
//     fragment hoisting); TLP from 32 waves/CU covers the lost ILP
//   - vsum dot accumulated incrementally so a0..a5 are not all live

#define SCALE 0.18033688011112042f   // log2(e)/8

typedef __bf16 bf16;
typedef bf16 v4bf __attribute__((ext_vector_type(4)));
typedef bf16 v8bf __attribute__((ext_vector_type(8)));
typedef float v4f __attribute__((ext_vector_type(4)));
typedef float v2f __attribute__((ext_vector_type(2)));

__device__ __forceinline__ v8bf pk8(float4 a, float4 b) {
    v8bf r;
    r[0] = (bf16)a.x; r[1] = (bf16)a.y; r[2] = (bf16)a.z; r[3] = (bf16)a.w;
    r[4] = (bf16)b.x; r[5] = (bf16)b.y; r[6] = (bf16)b.z; r[7] = (bf16)b.w;
    return r;
}
__device__ __forceinline__ float d4(float4 a, v4f w) {
    return a.x * w[0] + a.y * w[1] + a.z * w[2] + a.w * w[3];
}

__global__ __launch_bounds__(1024, 8)
void sda_kernel(const float* __restrict__ power,
                const int*   __restrict__ ele_i,
                const int*   __restrict__ azi_i,
                const float* __restrict__ ele_t,
                const float* __restrict__ azi_t,
                const float* __restrict__ Wq, const float* __restrict__ bq,
                const float* __restrict__ Wk, const float* __restrict__ bk,
                const float* __restrict__ Wv, const float* __restrict__ bv,
                float* __restrict__ out)
{
    extern __shared__ char smem[];
    char*  Kb   = smem;                      // 64 KB: K [key][dim] bf16, 128 B rows, blk16 ^= key&7
    float* vsum = (float*)(smem + 65536);    // 512 f32 (local key index)
    float* wvs  = (float*)(smem + 67584);    // 96 f32 col-sums of Wv + [96]=sum(bv)

    const int tid  = threadIdx.x;
    const int wave = tid >> 6;
    const int lane = tid & 63;
    const int l15  = lane & 15;
    const int quad = lane >> 4;

    // XCD-pair swizzle: hw blocks 8c+x -> logical x*64+c; logical pairs (2r,2r+1)
    // stay on one XCD so the range's power rows are shared in that XCD's L2.
    const int bid   = blockIdx.x;
    const int lj    = ((bid & 7) << 6) | (bid >> 3);
    const int range = lj >> 1;
    const int half  = lj & 1;

    const int keyrow0 = range * 512 + wave * 32;                    // wave's 32 key rows
    const int qrow    = range * 512 + half * 256 + wave * 16 + l15; // lane's query row

    // ---- wvsum: column sums of Wv (96) + bvsum, cooperative ----
    if (tid < 96) {
        float s = 0.f;
#pragma unroll 8
        for (int r = 0; r < 64; r++) s += Wv[r * 96 + tid];
        wvs[tid] = s;
    } else if (tid == 96) {
        float s = 0.f;
#pragma unroll
        for (int d = 0; d < 64; d++) s += bv[d];
        wvs[96] = s;
    }
    __syncthreads();

    // ---- query-row x fragment (16 queries per wave) ----
    v8bf xq[3];
    {
        const float* pr = power + (size_t)qrow * 64;
        float4 a0 = *(const float4*)(pr + quad * 8);
        float4 a1 = *(const float4*)(pr + quad * 8 + 4);
        xq[0] = pk8(a0, a1);
        float4 a2 = *(const float4*)(pr + 32 + quad * 8);
        float4 a3 = *(const float4*)(pr + 32 + quad * 8 + 4);
        xq[1] = pk8(a2, a3);
        int ie = ele_i[qrow];
        int ia = azi_i[qrow];
        const float* tb = (quad < 2) ? (ele_t + ie * 16 + quad * 8)
                                     : (azi_t + ia * 16 + (quad - 2) * 8);
        float4 a4 = *(const float4*)tb;
        float4 a5 = *(const float4*)(tb + 4);
        xq[2] = pk8(a4, a5);
    }

    // ---- Q^T = Wq @ x^T (operand swap), fold SCALE, transpose via own K region ----
    char* Sw = Kb + wave * 4096;   // wave's 32 K-rows; rows 0..15 used as Q scratch
#pragma unroll 1
    for (int mtd = 0; mtd < 4; mtd++) {
        v8bf wq3[3];
#pragma unroll
        for (int kt = 0; kt < 3; kt++) {
            const float* p = Wq + (mtd * 16 + l15) * 96 + kt * 32 + quad * 8;
            wq3[kt] = pk8(*(const float4*)p, *(const float4*)(p + 4));
        }
        float4 bq4 = *(const float4*)(bq + mtd * 16 + quad * 4);
        v4f acc = {0.f, 0.f, 0.f, 0.f};
#pragma unroll
        for (int kt = 0; kt < 3; kt++)
            acc = __builtin_amdgcn_mfma_f32_16x16x32_bf16(wq3[kt], xq[kt], acc, 0, 0, 0);
        v4bf o;
        o[0] = (bf16)((acc[0] + bq4.x) * SCALE);
        o[1] = (bf16)((acc[1] + bq4.y) * SCALE);
        o[2] = (bf16)((acc[2] + bq4.z) * SCALE);
        o[3] = (bf16)((acc[3] + bq4.w) * SCALE);
        *(v4bf*)(Sw + l15 * 128 +
                 ((((mtd * 2 + (quad >> 1)) ^ (l15 & 7)) << 4) | ((quad & 1) << 3))) = o;
    }
    v8bf qf[2];
#pragma unroll
    for (int kt = 0; kt < 2; kt++)
        qf[kt] = *(const v8bf*)(Sw + l15 * 128 + (((kt * 4 + quad) ^ (l15 & 7)) << 4));

    // ---- keys: one 16-row half at a time — x build + vsum + K GEMM ----
#pragma unroll 1
    for (int mt = 0; mt < 2; mt++) {
        int row = keyrow0 + mt * 16 + l15;
        v8bf xkl[3];
        float d;
        {
            const float* pr = power + (size_t)row * 64;
            float4 a0 = *(const float4*)(pr + quad * 8);
            float4 a1 = *(const float4*)(pr + quad * 8 + 4);
            xkl[0] = pk8(a0, a1);
            d  = d4(a0, *(const v4f*)(wvs + quad * 8))
               + d4(a1, *(const v4f*)(wvs + quad * 8 + 4));
            float4 a2 = *(const float4*)(pr + 32 + quad * 8);
            float4 a3 = *(const float4*)(pr + 32 + quad * 8 + 4);
            xkl[1] = pk8(a2, a3);
            d += d4(a2, *(const v4f*)(wvs + 32 + quad * 8))
               + d4(a3, *(const v4f*)(wvs + 32 + quad * 8 + 4));
            int ie = ele_i[row];
            int ia = azi_i[row];
            const float* tb = (quad < 2) ? (ele_t + ie * 16 + quad * 8)
                                         : (azi_t + ia * 16 + (quad - 2) * 8);
            float4 a4 = *(const float4*)tb;
            float4 a5 = *(const float4*)(tb + 4);
            xkl[2] = pk8(a4, a5);
            d += d4(a4, *(const v4f*)(wvs + 64 + quad * 8))
               + d4(a5, *(const v4f*)(wvs + 64 + quad * 8 + 4));
        }
        d += __shfl_xor(d, 16);
        d += __shfl_xor(d, 32);
        if (quad == 0) vsum[wave * 32 + mt * 16 + l15] = d + wvs[96];

        int keyb = wave * 32 + mt * 16 + l15;
#pragma unroll 1
        for (int mtd = 0; mtd < 4; mtd++) {
            v8bf wk3[3];
#pragma unroll
            for (int kt = 0; kt < 3; kt++) {
                const float* p = Wk + (mtd * 16 + l15) * 96 + kt * 32 + quad * 8;
                wk3[kt] = pk8(*(const float4*)p, *(const float4*)(p + 4));
            }
            float4 bk4 = *(const float4*)(bk + mtd * 16 + quad * 4);
            v4f acc = {0.f, 0.f, 0.f, 0.f};
#pragma unroll
            for (int kt = 0; kt < 3; kt++)
                acc = __builtin_amdgcn_mfma_f32_16x16x32_bf16(wk3[kt], xkl[kt], acc, 0, 0, 0);
            v4bf o;
            o[0] = (bf16)(acc[0] + bk4.x);
            o[1] = (bf16)(acc[1] + bk4.y);
            o[2] = (bf16)(acc[2] + bk4.z);
            o[3] = (bf16)(acc[3] + bk4.w);
            *(v4bf*)(Kb + keyb * 128 +
                     ((((mtd * 2 + (quad >> 1)) ^ (keyb & 7)) << 4) | ((quad & 1) << 3))) = o;
        }
    }
    __syncthreads();

    // ---- Phase B: S^T = K @ Q^T, exp2, weighted accumulate with vsum ----
    v2f oacc = {0.f, 0.f};
    v2f lacc = {0.f, 0.f};
#pragma unroll 1
    for (int t = 0; t < 16; t++) {
        v8bf kf[2][2];
#pragma unroll
        for (int mtk = 0; mtk < 2; mtk++)
#pragma unroll
            for (int kt = 0; kt < 2; kt++) {
                int key = t * 32 + mtk * 16 + l15;
                kf[mtk][kt] = *(const v8bf*)(Kb + key * 128 + (((kt * 4 + quad) ^ (key & 7)) << 4));
            }
        v4f vs[2];
#pragma unroll
        for (int mtk = 0; mtk < 2; mtk++)
            vs[mtk] = *(const v4f*)(vsum + t * 32 + mtk * 16 + quad * 4);
#pragma unroll
        for (int mtk = 0; mtk < 2; mtk++) {
            v4f acc = {0.f, 0.f, 0.f, 0.f};
            acc = __builtin_amdgcn_mfma_f32_16x16x32_bf16(kf[mtk][0], qf[0], acc, 0, 0, 0);
            acc = __builtin_amdgcn_mfma_f32_16x16x32_bf16(kf[mtk][1], qf[1], acc, 0, 0, 0);
            float p0 = __builtin_amdgcn_exp2f(acc[0]);
            float p1 = __builtin_amdgcn_exp2f(acc[1]);
            float p2 = __builtin_amdgcn_exp2f(acc[2]);
            float p3 = __builtin_amdgcn_exp2f(acc[3]);
            v2f p01 = {p0, p1};
            v2f p23 = {p2, p3};
            v2f v01 = {vs[mtk][0], vs[mtk][1]};
            v2f v23 = {vs[mtk][2], vs[mtk][3]};
            lacc += p01 + p23;                 // v_pk_add_f32
            oacc += p01 * v01 + p23 * v23;     // v_pk_fma_f32
        }
    }

    // ---- epilogue: reduce over key-quads, out = osum/lsum ----
    float lv = lacc[0] + lacc[1];
    lv += __shfl_xor(lv, 16);
    lv += __shfl_xor(lv, 32);
    float ov = oacc[0] + oacc[1];
    ov += __shfl_xor(ov, 16);
    ov += __shfl_xor(ov, 32);
    if (quad == 0) out[range * 512 + half * 256 + wave * 16 + l15] = ov / lv;
}

extern "C" void kernel_launch(void* const* d_in, const int* in_sizes, int n_in,
                              void* d_out, int out_size, void* d_ws, size_t ws_size,
                              hipStream_t stream) {
    const float* power = (const float*)d_in[0];
    const int*   ele_i = (const int*)d_in[1];
    // d_in[2] = range_indices: unused by the reference (positional reshape)
    const int*   azi_i = (const int*)d_in[3];
    const float* ele_t = (const float*)d_in[4];
    const float* azi_t = (const float*)d_in[5];
    const float* Wq = (const float*)d_in[6];
    const float* bq = (const float*)d_in[7];
    const float* Wk = (const float*)d_in[8];
    const float* bk = (const float*)d_in[9];
    const float* Wv = (const float*)d_in[10];
    const float* bv = (const float*)d_in[11];
    float* out = (float*)d_out;

    const int lds_bytes = 65536 + 2048 + 512;   // Kb + vsum + wvs(97, padded)
    (void)hipFuncSetAttribute(reinterpret_cast<const void*>(sda_kernel),
                              hipFuncAttributeMaxDynamicSharedMemorySize, lds_bytes);
    sda_kernel<<<512, 1024, lds_bytes, stream>>>(power, ele_i, azi_i, ele_t, azi_t,
                                                 Wq, bq, Wk, bk, Wv, bv, out);
}

// Round 3
// 161.825 us; speedup vs baseline: 1.1437x; 1.1437x over previous
//
#include <hip/hip_runtime.h>

// SparseDopplerAttention on gfx950 — R6: two-kernel decomposition.
// R5 post-mortem: Phase A (QKV build: x-load + weight loads + GEMMs) dominates;
// R4/R5's query-split duplicated it => 2x time. Single-kernel coupling of build
// state (x frags + weight frags) with attend state (qf) also forced spills at
// the 64-VGPR / 8-waves-per-SIMD budget.
// R6 decouples:
//   k1 sda_qkv: per-wave 16 rows -> Q (bf16, bias+SCALE folded), K (bf16),
//      vsum = x . colsum(Wv) + sum(bv) (f32), written row-major to d_ws.
//      Tiny register state -> 8 waves/SIMD, memory-bound (~50 MB traffic).
//   k2 sda_attn: block=(range,half). Stage K-tile (64 KB, XOR-swizzled
//      ds_writes) + vsum (2 KB) to LDS; each wave attends 16 queries over all
//      512 keys (no-max softmax in log2 domain, exact partial-free sums).
//      ~45 VGPR -> 8 waves/SIMD, 2 blocks/CU (133 KB LDS), 32 waves/CU,
//      and NO duplicated GEMM work (only the 64 KB stage happens twice/range).
// Matching XCD swizzle in both kernels keeps a range's K/Q in its producer L2.
// Fallback: proven R3 mono-kernel if ws_size is insufficient.

#define SCALE 0.18033688011112042f   // log2(e)/8

typedef __bf16 bf16;
typedef bf16 v4bf __attribute__((ext_vector_type(4)));
typedef bf16 v8bf __attribute__((ext_vector_type(8)));
typedef float v4f __attribute__((ext_vector_type(4)));
typedef float v2f __attribute__((ext_vector_type(2)));

__device__ __forceinline__ v8bf pk8(float4 a, float4 b) {
    v8bf r;
    r[0] = (bf16)a.x; r[1] = (bf16)a.y; r[2] = (bf16)a.z; r[3] = (bf16)a.w;
    r[4] = (bf16)b.x; r[5] = (bf16)b.y; r[6] = (bf16)b.z; r[7] = (bf16)b.w;
    return r;
}
__device__ __forceinline__ float d4(float4 a, v4f w) {
    return a.x * w[0] + a.y * w[1] + a.z * w[2] + a.w * w[3];
}

// ---------------- kernel 1: QKV build (512 blocks x 1024 thr, 256 rows/block) ----
__global__ __launch_bounds__(1024, 8)
void sda_qkv(const float* __restrict__ power,
             const int*   __restrict__ ele_i,
             const int*   __restrict__ azi_i,
             const float* __restrict__ ele_t,
             const float* __restrict__ azi_t,
             const float* __restrict__ Wq, const float* __restrict__ bq,
             const float* __restrict__ Wk, const float* __restrict__ bk,
             const float* __restrict__ Wv, const float* __restrict__ bv,
             bf16* __restrict__ Qg, bf16* __restrict__ Kg,
             float* __restrict__ vsg)
{
    __shared__ float wvs[98];            // 96 col-sums of Wv + [96]=sum(bv)
    __shared__ char  scratch[16 * 2048]; // per-wave 2 KB transpose scratch

    const int tid  = threadIdx.x;
    const int wave = tid >> 6;
    const int lane = tid & 63;
    const int l15  = lane & 15;
    const int quad = lane >> 4;

    // same swizzle as k2 so producer and consumer of a range share an XCD L2
    const int bid = blockIdx.x;
    const int lj  = ((bid & 7) << 6) | (bid >> 3);
    const int row = lj * 256 + wave * 16 + l15;   // this lane's row

    if (tid < 96) {
        float s = 0.f;
#pragma unroll 8
        for (int r = 0; r < 64; r++) s += Wv[r * 96 + tid];
        wvs[tid] = s;
    } else if (tid == 96) {
        float s = 0.f;
#pragma unroll
        for (int d = 0; d < 64; d++) s += bv[d];
        wvs[96] = s;
    }
    __syncthreads();

    // ---- build x fragments (bf16) + fp32 vsum, incrementally (low pressure) ----
    v8bf xa[3];
    float d;
    {
        const float* pr = power + (size_t)row * 64;
        float4 a0 = *(const float4*)(pr + quad * 8);
        float4 a1 = *(const float4*)(pr + quad * 8 + 4);
        xa[0] = pk8(a0, a1);
        d  = d4(a0, *(const v4f*)(wvs + quad * 8))
           + d4(a1, *(const v4f*)(wvs + quad * 8 + 4));
        float4 a2 = *(const float4*)(pr + 32 + quad * 8);
        float4 a3 = *(const float4*)(pr + 32 + quad * 8 + 4);
        xa[1] = pk8(a2, a3);
        d += d4(a2, *(const v4f*)(wvs + 32 + quad * 8))
           + d4(a3, *(const v4f*)(wvs + 32 + quad * 8 + 4));
        int ie = ele_i[row];
        int ia = azi_i[row];
        const float* tb = (quad < 2) ? (ele_t + ie * 16 + quad * 8)
                                     : (azi_t + ia * 16 + (quad - 2) * 8);
        float4 a4 = *(const float4*)tb;
        float4 a5 = *(const float4*)(tb + 4);
        xa[2] = pk8(a4, a5);
        d += d4(a4, *(const v4f*)(wvs + 64 + quad * 8))
           + d4(a5, *(const v4f*)(wvs + 64 + quad * 8 + 4));
    }
    d += __shfl_xor(d, 16);
    d += __shfl_xor(d, 32);
    if (quad == 0) vsg[row] = d + wvs[96];

    char* Sw = scratch + wave * 2048;

    // ---- Q^T = Wq @ x^T (16x16x32, operand swap), fold bias+SCALE, transpose, store ----
#pragma unroll 1
    for (int mtd = 0; mtd < 4; mtd++) {
        v8bf w3[3];
#pragma unroll
        for (int kt = 0; kt < 3; kt++) {
            const float* p = Wq + (mtd * 16 + l15) * 96 + kt * 32 + quad * 8;
            w3[kt] = pk8(*(const float4*)p, *(const float4*)(p + 4));
        }
        float4 b4 = *(const float4*)(bq + mtd * 16 + quad * 4);
        v4f acc = {0.f, 0.f, 0.f, 0.f};
#pragma unroll
        for (int kt = 0; kt < 3; kt++)
            acc = __builtin_amdgcn_mfma_f32_16x16x32_bf16(w3[kt], xa[kt], acc, 0, 0, 0);
        v4bf o;
        o[0] = (bf16)((acc[0] + b4.x) * SCALE);
        o[1] = (bf16)((acc[1] + b4.y) * SCALE);
        o[2] = (bf16)((acc[2] + b4.z) * SCALE);
        o[3] = (bf16)((acc[3] + b4.w) * SCALE);
        *(v4bf*)(Sw + l15 * 128 +
                 ((((mtd * 2 + (quad >> 1)) ^ (l15 & 7)) << 4) | ((quad & 1) << 3))) = o;
    }
#pragma unroll
    for (int kt = 0; kt < 2; kt++) {
        v8bf q = *(const v8bf*)(Sw + l15 * 128 + (((kt * 4 + quad) ^ (l15 & 7)) << 4));
        *(v8bf*)(Qg + (size_t)row * 64 + (kt * 4 + quad) * 8) = q;
    }

    // ---- K^T = Wk @ x^T, transpose, store (reuse scratch; same-wave DS in-order) ----
#pragma unroll 1
    for (int mtd = 0; mtd < 4; mtd++) {
        v8bf w3[3];
#pragma unroll
        for (int kt = 0; kt < 3; kt++) {
            const float* p = Wk + (mtd * 16 + l15) * 96 + kt * 32 + quad * 8;
            w3[kt] = pk8(*(const float4*)p, *(const float4*)(p + 4));
        }
        float4 b4 = *(const float4*)(bk + mtd * 16 + quad * 4);
        v4f acc = {0.f, 0.f, 0.f, 0.f};
#pragma unroll
        for (int kt = 0; kt < 3; kt++)
            acc = __builtin_amdgcn_mfma_f32_16x16x32_bf16(w3[kt], xa[kt], acc, 0, 0, 0);
        v4bf o;
        o[0] = (bf16)(acc[0] + b4.x);
        o[1] = (bf16)(acc[1] + b4.y);
        o[2] = (bf16)(acc[2] + b4.z);
        o[3] = (bf16)(acc[3] + b4.w);
        *(v4bf*)(Sw + l15 * 128 +
                 ((((mtd * 2 + (quad >> 1)) ^ (l15 & 7)) << 4) | ((quad & 1) << 3))) = o;
    }
#pragma unroll
    for (int kt = 0; kt < 2; kt++) {
        v8bf k = *(const v8bf*)(Sw + l15 * 128 + (((kt * 4 + quad) ^ (l15 & 7)) << 4));
        *(v8bf*)(Kg + (size_t)row * 64 + (kt * 4 + quad) * 8) = k;
    }
}

// ---------------- kernel 2: attention (512 blocks x 1024 thr, block=(range,half)) ----
__global__ __launch_bounds__(1024, 8)
void sda_attn(const bf16* __restrict__ Qg, const bf16* __restrict__ Kg,
              const float* __restrict__ vsg, float* __restrict__ out)
{
    extern __shared__ char smem[];
    char*  Kb   = smem;                   // 64 KB swizzled K tile
    float* vs_l = (float*)(smem + 65536); // 512 f32

    const int tid  = threadIdx.x;
    const int wave = tid >> 6;
    const int lane = tid & 63;
    const int l15  = lane & 15;
    const int quad = lane >> 4;

    const int bid   = blockIdx.x;
    const int lj    = ((bid & 7) << 6) | (bid >> 3);
    const int range = lj >> 1;
    const int half  = lj & 1;

    // ---- stage K tile (reg-staged, XOR-swizzled writes) + vsum ----
    const bf16* Ksrc = Kg + (size_t)range * 512 * 64;
#pragma unroll
    for (int i = 0; i < 4; i++) {
        int c = tid + i * 1024;          // 16-B chunk index, 4096 chunks
        int r = c >> 3;                  // key row 0..511
        int j = c & 7;                   // 16-B block within row
        v8bf kv = *(const v8bf*)(Ksrc + r * 64 + j * 8);
        *(v8bf*)(Kb + r * 128 + ((j ^ (r & 7)) << 4)) = kv;
    }
    if (tid < 512) vs_l[tid] = vsg[range * 512 + tid];

    // queries: straight from global (row-major == B-fragment layout)
    const int qrow = range * 512 + half * 256 + wave * 16 + l15;
    v8bf qf[2];
#pragma unroll
    for (int kt = 0; kt < 2; kt++)
        qf[kt] = *(const v8bf*)(Qg + (size_t)qrow * 64 + (kt * 4 + quad) * 8);
    __syncthreads();

    // ---- S^T = K @ Q^T, exp2, weighted accumulate with vsum ----
    v2f oacc = {0.f, 0.f};
    v2f lacc = {0.f, 0.f};
#pragma unroll 2
    for (int t = 0; t < 16; t++) {
        v8bf kf[2][2];
#pragma unroll
        for (int mtk = 0; mtk < 2; mtk++)
#pragma unroll
            for (int kt = 0; kt < 2; kt++) {
                int key = t * 32 + mtk * 16 + l15;
                kf[mtk][kt] = *(const v8bf*)(Kb + key * 128 + (((kt * 4 + quad) ^ (key & 7)) << 4));
            }
        v4f vs[2];
#pragma unroll
        for (int mtk = 0; mtk < 2; mtk++)
            vs[mtk] = *(const v4f*)(vs_l + t * 32 + mtk * 16 + quad * 4);
#pragma unroll
        for (int mtk = 0; mtk < 2; mtk++) {
            v4f acc = {0.f, 0.f, 0.f, 0.f};
            acc = __builtin_amdgcn_mfma_f32_16x16x32_bf16(kf[mtk][0], qf[0], acc, 0, 0, 0);
            acc = __builtin_amdgcn_mfma_f32_16x16x32_bf16(kf[mtk][1], qf[1], acc, 0, 0, 0);
            float p0 = __builtin_amdgcn_exp2f(acc[0]);
            float p1 = __builtin_amdgcn_exp2f(acc[1]);
            float p2 = __builtin_amdgcn_exp2f(acc[2]);
            float p3 = __builtin_amdgcn_exp2f(acc[3]);
            v2f p01 = {p0, p1};
            v2f p23 = {p2, p3};
            v2f v01 = {vs[mtk][0], vs[mtk][1]};
            v2f v23 = {vs[mtk][2], vs[mtk][3]};
            lacc += p01 + p23;
            oacc += p01 * v01 + p23 * v23;
        }
    }

    float lv = lacc[0] + lacc[1];
    lv += __shfl_xor(lv, 16);
    lv += __shfl_xor(lv, 32);
    float ov = oacc[0] + oacc[1];
    ov += __shfl_xor(ov, 16);
    ov += __shfl_xor(ov, 32);
    if (quad == 0) out[qrow] = ov / lv;
}

// ---------------- fallback: proven R3 mono-kernel (ws too small) ----------------
__global__ __launch_bounds__(1024, 4)
void sda_mono(const float* __restrict__ power,
              const int*   __restrict__ ele_i,
              const int*   __restrict__ azi_i,
              const float* __restrict__ ele_t,
              const float* __restrict__ azi_t,
              const float* __restrict__ Wq, const float* __restrict__ bq,
              const float* __restrict__ Wk, const float* __restrict__ bk,
              const float* __restrict__ Wv, const float* __restrict__ bv,
              float* __restrict__ out)
{
    extern __shared__ char smem[];
    char*  Kb   = smem;
    float* vsum = (float*)(smem + 65536);
    float* wvs  = (float*)(smem + 67584);

    const int tid  = threadIdx.x;
    const int wave = tid >> 6;
    const int lane = tid & 63;
    const int l15  = lane & 15;
    const int quad = lane >> 4;
    const int rowbase = blockIdx.x * 512 + wave * 32;

    if (tid < 96) {
        float s = 0.f;
#pragma unroll 8
        for (int r = 0; r < 64; r++) s += Wv[r * 96 + tid];
        wvs[tid] = s;
    } else if (tid == 96) {
        float s = 0.f;
#pragma unroll
        for (int d = 0; d < 64; d++) s += bv[d];
        wvs[96] = s;
    }
    __syncthreads();

    v4f w0 = *(const v4f*)(wvs + quad * 8);
    v4f w1 = *(const v4f*)(wvs + quad * 8 + 4);
    v4f w2 = *(const v4f*)(wvs + 32 + quad * 8);
    v4f w3 = *(const v4f*)(wvs + 32 + quad * 8 + 4);
    v4f w4 = *(const v4f*)(wvs + 64 + quad * 8);
    v4f w5 = *(const v4f*)(wvs + 64 + quad * 8 + 4);
    const float bvs = wvs[96];

    v8bf xa[2][3];
#pragma unroll
    for (int mt = 0; mt < 2; mt++) {
        int row = rowbase + mt * 16 + l15;
        const float* pr = power + (size_t)row * 64;
        float4 a0 = *(const float4*)(pr + quad * 8);
        float4 a1 = *(const float4*)(pr + quad * 8 + 4);
        float4 a2 = *(const float4*)(pr + 32 + quad * 8);
        float4 a3 = *(const float4*)(pr + 32 + quad * 8 + 4);
        int ie = ele_i[row];
        int ia = azi_i[row];
        const float* tb = (quad < 2) ? (ele_t + ie * 16 + quad * 8)
                                     : (azi_t + ia * 16 + (quad - 2) * 8);
        float4 a4 = *(const float4*)tb;
        float4 a5 = *(const float4*)(tb + 4);
        xa[mt][0] = pk8(a0, a1);
        xa[mt][1] = pk8(a2, a3);
        xa[mt][2] = pk8(a4, a5);
        float d = d4(a0, w0) + d4(a1, w1) + d4(a2, w2) + d4(a3, w3) + d4(a4, w4) + d4(a5, w5);
        d += __shfl_xor(d, 16);
        d += __shfl_xor(d, 32);
        if (quad == 0) vsum[wave * 32 + mt * 16 + l15] = d + bvs;
    }

    char* Sw = Kb + wave * 4096;
#pragma unroll
    for (int mtd = 0; mtd < 4; mtd++) {
        v8bf wq3[3];
#pragma unroll
        for (int kt = 0; kt < 3; kt++) {
            const float* p = Wq + (mtd * 16 + l15) * 96 + kt * 32 + quad * 8;
            wq3[kt] = pk8(*(const float4*)p, *(const float4*)(p + 4));
        }
        float4 bq4 = *(const float4*)(bq + mtd * 16 + quad * 4);
#pragma unroll
        for (int ntr = 0; ntr < 2; ntr++) {
            v4f acc = {0.f, 0.f, 0.f, 0.f};
#pragma unroll
            for (int kt = 0; kt < 3; kt++)
                acc = __builtin_amdgcn_mfma_f32_16x16x32_bf16(wq3[kt], xa[ntr][kt], acc, 0, 0, 0);
            int row = ntr * 16 + l15;
            v4bf o;
            o[0] = (bf16)((acc[0] + bq4.x) * SCALE);
            o[1] = (bf16)((acc[1] + bq4.y) * SCALE);
            o[2] = (bf16)((acc[2] + bq4.z) * SCALE);
            o[3] = (bf16)((acc[3] + bq4.w) * SCALE);
            *(v4bf*)(Sw + row * 128 +
                     ((((mtd * 2 + (quad >> 1)) ^ (row & 7)) << 4) | ((quad & 1) << 3))) = o;
        }
    }
    v8bf qf[2][2];
#pragma unroll
    for (int nt = 0; nt < 2; nt++)
#pragma unroll
        for (int kt = 0; kt < 2; kt++)
            qf[nt][kt] = *(const v8bf*)(Sw + (nt * 16 + l15) * 128 +
                                        (((kt * 4 + quad) ^ (l15 & 7)) << 4));

#pragma unroll
    for (int mtd = 0; mtd < 4; mtd++) {
        v8bf wk3[3];
#pragma unroll
        for (int kt = 0; kt < 3; kt++) {
            const float* p = Wk + (mtd * 16 + l15) * 96 + kt * 32 + quad * 8;
            wk3[kt] = pk8(*(const float4*)p, *(const float4*)(p + 4));
        }
        float4 bk4 = *(const float4*)(bk + mtd * 16 + quad * 4);
#pragma unroll
        for (int ntr = 0; ntr < 2; ntr++) {
            v4f acc = {0.f, 0.f, 0.f, 0.f};
#pragma unroll
            for (int kt = 0; kt < 3; kt++)
                acc = __builtin_amdgcn_mfma_f32_16x16x32_bf16(wk3[kt], xa[ntr][kt], acc, 0, 0, 0);
            int keyb = wave * 32 + ntr * 16 + l15;
            v4bf o;
            o[0] = (bf16)(acc[0] + bk4.x);
            o[1] = (bf16)(acc[1] + bk4.y);
            o[2] = (bf16)(acc[2] + bk4.z);
            o[3] = (bf16)(acc[3] + bk4.w);
            *(v4bf*)(Kb + keyb * 128 +
                     ((((mtd * 2 + (quad >> 1)) ^ (keyb & 7)) << 4) | ((quad & 1) << 3))) = o;
        }
    }
    __syncthreads();

    float osum[2] = {0.f, 0.f};
    float lsum[2] = {0.f, 0.f};
#pragma unroll 2
    for (int t = 0; t < 16; t++) {
        v8bf kf[2][2];
#pragma unroll
        for (int mtk = 0; mtk < 2; mtk++)
#pragma unroll
            for (int kt = 0; kt < 2; kt++) {
                int key = t * 32 + mtk * 16 + l15;
                kf[mtk][kt] = *(const v8bf*)(Kb + key * 128 + (((kt * 4 + quad) ^ (key & 7)) << 4));
            }
        v4f vs[2];
#pragma unroll
        for (int mtk = 0; mtk < 2; mtk++)
            vs[mtk] = *(const v4f*)(vsum + t * 32 + mtk * 16 + quad * 4);
#pragma unroll
        for (int mtk = 0; mtk < 2; mtk++) {
#pragma unroll
            for (int nt = 0; nt < 2; nt++) {
                v4f acc = {0.f, 0.f, 0.f, 0.f};
                acc = __builtin_amdgcn_mfma_f32_16x16x32_bf16(kf[mtk][0], qf[nt][0], acc, 0, 0, 0);
                acc = __builtin_amdgcn_mfma_f32_16x16x32_bf16(kf[mtk][1], qf[nt][1], acc, 0, 0, 0);
                float p0 = __builtin_amdgcn_exp2f(acc[0]);
                float p1 = __builtin_amdgcn_exp2f(acc[1]);
                float p2 = __builtin_amdgcn_exp2f(acc[2]);
                float p3 = __builtin_amdgcn_exp2f(acc[3]);
                lsum[nt] += (p0 + p1) + (p2 + p3);
                osum[nt] += ((p0 * vs[mtk][0] + p1 * vs[mtk][1]) +
                             (p2 * vs[mtk][2] + p3 * vs[mtk][3]));
            }
        }
    }

#pragma unroll
    for (int nt = 0; nt < 2; nt++) {
        float lv = lsum[nt];
        lv += __shfl_xor(lv, 16);
        lv += __shfl_xor(lv, 32);
        float ov = osum[nt];
        ov += __shfl_xor(ov, 16);
        ov += __shfl_xor(ov, 32);
        if (quad == 0) out[rowbase + nt * 16 + l15] = ov / lv;
    }
}

extern "C" void kernel_launch(void* const* d_in, const int* in_sizes, int n_in,
                              void* d_out, int out_size, void* d_ws, size_t ws_size,
                              hipStream_t stream) {
    const float* power = (const float*)d_in[0];
    const int*   ele_i = (const int*)d_in[1];
    // d_in[2] = range_indices: unused by the reference (positional reshape)
    const int*   azi_i = (const int*)d_in[3];
    const float* ele_t = (const float*)d_in[4];
    const float* azi_t = (const float*)d_in[5];
    const float* Wq = (const float*)d_in[6];
    const float* bq = (const float*)d_in[7];
    const float* Wk = (const float*)d_in[8];
    const float* bk = (const float*)d_in[9];
    const float* Wv = (const float*)d_in[10];
    const float* bv = (const float*)d_in[11];
    float* out = (float*)d_out;

    const size_t NROWS = 131072;                 // 256 ranges x 512
    const size_t q_bytes = NROWS * 64 * sizeof(bf16);   // 16 MB
    const size_t need = 2 * q_bytes + NROWS * sizeof(float);

    if (ws_size >= need) {
        bf16* Qg  = (bf16*)d_ws;
        bf16* Kg  = Qg + NROWS * 64;
        float* vsg = (float*)((char*)d_ws + 2 * q_bytes);

        sda_qkv<<<512, 1024, 0, stream>>>(power, ele_i, azi_i, ele_t, azi_t,
                                          Wq, bq, Wk, bk, Wv, bv, Qg, Kg, vsg);

        const int lds2 = 65536 + 2048;           // K tile + vsum
        (void)hipFuncSetAttribute(reinterpret_cast<const void*>(sda_attn),
                                  hipFuncAttributeMaxDynamicSharedMemorySize, lds2);
        sda_attn<<<512, 1024, lds2, stream>>>(Qg, Kg, vsg, out);
    } else {
        const int lds_bytes = 65536 + 2048 + 512;
        (void)hipFuncSetAttribute(reinterpret_cast<const void*>(sda_mono),
                                  hipFuncAttributeMaxDynamicSharedMemorySize, lds_bytes);
        sda_mono<<<256, 1024, lds_bytes, stream>>>(power, ele_i, azi_i, ele_t, azi_t,
                                                   Wq, bq, Wk, bk, Wv, bv, out);
    }
}

// Round 4
// 110.689 us; speedup vs baseline: 1.6721x; 1.4620x over previous
//
#include <hip/hip_runtime.h>

// SparseDopplerAttention on gfx950 — R7.
// Identity (R3): out[q] = (sum_k P[q,k]*vsum[k]) / (sum_k P[q,k]),
//   vsum[k] = x[k] . colsum(Wv) + sum(bv)  (fp32) — V GEMM / PV GEMM eliminated.
// R6 post-mortem: QKV build is pure latency — every wave re-loads Wq/Wk from
// global (393 MB of L2-latency-bound reads chip-wide), serialized by vmcnt
// drains in the mtd loops. R7 = proven R3 structure + weights staged ONCE per
// block into LDS as bf16 fragments (conflict-free stride-192 layout), biases in
// LDS, and the cold power/index loads pre-issued at kernel entry so HBM latency
// hides under the staging prologue. Phase B (S^T=K@Q^T, no-max log2 softmax,
// vsum-weighted accumulate) unchanged from R3.

#define SCALE 0.18033688011112042f   // log2(e)/8

typedef __bf16 bf16;
typedef bf16 v4bf __attribute__((ext_vector_type(4)));
typedef bf16 v8bf __attribute__((ext_vector_type(8)));
typedef float v4f __attribute__((ext_vector_type(4)));

__device__ __forceinline__ v8bf pk8(float4 a, float4 b) {
    v8bf r;
    r[0] = (bf16)a.x; r[1] = (bf16)a.y; r[2] = (bf16)a.z; r[3] = (bf16)a.w;
    r[4] = (bf16)b.x; r[5] = (bf16)b.y; r[6] = (bf16)b.z; r[7] = (bf16)b.w;
    return r;
}
__device__ __forceinline__ float d4(float4 a, v4f w) {
    return a.x * w[0] + a.y * w[1] + a.z * w[2] + a.w * w[3];
}

__global__ __launch_bounds__(1024, 4)
void sda_kernel(const float* __restrict__ power,
                const int*   __restrict__ ele_i,
                const int*   __restrict__ azi_i,
                const float* __restrict__ ele_t,
                const float* __restrict__ azi_t,
                const float* __restrict__ Wq, const float* __restrict__ bq,
                const float* __restrict__ Wk, const float* __restrict__ bk,
                const float* __restrict__ Wv, const float* __restrict__ bv,
                float* __restrict__ out)
{
    extern __shared__ char smem[];
    char*  Kb   = smem;                      // 64 KB: K [key][dim] bf16, 128 B rows, blk16 ^= key&7
    float* vsum = (float*)(smem + 65536);    // 512 f32
    float* wvs  = (float*)(smem + 67584);    // 96 col-sums of Wv + [96]=sum(bv)
    bf16*  WqL  = (bf16*)(smem + 68096);     // 12 KB: Wq bf16 row-major [64][96]
    bf16*  WkL  = (bf16*)(smem + 80384);     // 12 KB: Wk bf16 row-major [64][96]
    float* bqL  = (float*)(smem + 92672);    // 64 f32
    float* bkL  = (float*)(smem + 92928);    // 64 f32

    const int tid  = threadIdx.x;
    const int wave = tid >> 6;
    const int lane = tid & 63;
    const int l15  = lane & 15;
    const int quad = lane >> 4;
    const int rowbase = blockIdx.x * 512 + wave * 32;   // this wave's 32 rows

    // ---- pre-issue the cold streaming loads (power rows + indices) ----
    float4 A[2][4];
    int IE[2], IA[2];
#pragma unroll
    for (int mt = 0; mt < 2; mt++) {
        int row = rowbase + mt * 16 + l15;
        const float* pr = power + (size_t)row * 64;
        A[mt][0] = *(const float4*)(pr + quad * 8);
        A[mt][1] = *(const float4*)(pr + quad * 8 + 4);
        A[mt][2] = *(const float4*)(pr + 32 + quad * 8);
        A[mt][3] = *(const float4*)(pr + 32 + quad * 8 + 4);
        IE[mt] = ele_i[row];
        IA[mt] = azi_i[row];
    }

    // ---- prologue: stage Wq/Wk -> bf16 LDS, biases -> LDS, Wv col-sums ----
#pragma unroll
    for (int i = 0; i < 6; i++) {
        int idx = tid + i * 1024;            // 6144 elements each
        WqL[idx] = (bf16)Wq[idx];
        WkL[idx] = (bf16)Wk[idx];
    }
    if (tid < 64) { bqL[tid] = bq[tid]; bkL[tid] = bk[tid]; }
    if (tid < 96) {
        float s = 0.f;
#pragma unroll 16
        for (int r = 0; r < 64; r++) s += Wv[r * 96 + tid];
        wvs[tid] = s;
    } else if (tid == 96) {
        float s = 0.f;
#pragma unroll
        for (int d = 0; d < 64; d++) s += bv[d];
        wvs[96] = s;
    }
    __syncthreads();

    // per-lane wvsum slice
    v4f w0 = *(const v4f*)(wvs + quad * 8);
    v4f w1 = *(const v4f*)(wvs + quad * 8 + 4);
    v4f w2 = *(const v4f*)(wvs + 32 + quad * 8);
    v4f w3 = *(const v4f*)(wvs + 32 + quad * 8 + 4);
    v4f w4 = *(const v4f*)(wvs + 64 + quad * 8);
    v4f w5 = *(const v4f*)(wvs + 64 + quad * 8 + 4);
    const float bvs = wvs[96];

    // ---- x fragments (bf16) + fp32 vsum ----
    v8bf xa[2][3];
#pragma unroll
    for (int mt = 0; mt < 2; mt++) {
        const float* tb = (quad < 2) ? (ele_t + IE[mt] * 16 + quad * 8)
                                     : (azi_t + IA[mt] * 16 + (quad - 2) * 8);
        float4 a4 = *(const float4*)tb;
        float4 a5 = *(const float4*)(tb + 4);
        xa[mt][0] = pk8(A[mt][0], A[mt][1]);
        xa[mt][1] = pk8(A[mt][2], A[mt][3]);
        xa[mt][2] = pk8(a4, a5);
        float d = d4(A[mt][0], w0) + d4(A[mt][1], w1) + d4(A[mt][2], w2)
                + d4(A[mt][3], w3) + d4(a4, w4) + d4(a5, w5);
        d += __shfl_xor(d, 16);
        d += __shfl_xor(d, 32);
        if (quad == 0) vsum[wave * 32 + mt * 16 + l15] = d + bvs;
    }

    // ---- Q^T = Wq @ x^T (weights from LDS), fold SCALE, transpose via own K region ----
    char* Sw = Kb + wave * 4096;   // this wave's 32 K-rows; used first as Q scratch
#pragma unroll 1
    for (int mtd = 0; mtd < 4; mtd++) {
        const bf16* wrow = WqL + (mtd * 16 + l15) * 96;
        v8bf wq3[3];
#pragma unroll
        for (int kt = 0; kt < 3; kt++)
            wq3[kt] = *(const v8bf*)(wrow + kt * 32 + quad * 8);
        float4 bq4 = *(const float4*)(bqL + mtd * 16 + quad * 4);
#pragma unroll
        for (int ntr = 0; ntr < 2; ntr++) {
            v4f acc = {0.f, 0.f, 0.f, 0.f};
#pragma unroll
            for (int kt = 0; kt < 3; kt++)
                acc = __builtin_amdgcn_mfma_f32_16x16x32_bf16(wq3[kt], xa[ntr][kt], acc, 0, 0, 0);
            int row = ntr * 16 + l15;   // local query
            v4bf o;
            o[0] = (bf16)((acc[0] + bq4.x) * SCALE);
            o[1] = (bf16)((acc[1] + bq4.y) * SCALE);
            o[2] = (bf16)((acc[2] + bq4.z) * SCALE);
            o[3] = (bf16)((acc[3] + bq4.w) * SCALE);
            *(v4bf*)(Sw + row * 128 +
                     ((((mtd * 2 + (quad >> 1)) ^ (row & 7)) << 4) | ((quad & 1) << 3))) = o;
        }
    }
    v8bf qf[2][2];
#pragma unroll
    for (int nt = 0; nt < 2; nt++)
#pragma unroll
        for (int kt = 0; kt < 2; kt++)
            qf[nt][kt] = *(const v8bf*)(Sw + (nt * 16 + l15) * 128 +
                                        (((kt * 4 + quad) ^ (l15 & 7)) << 4));

    // ---- K^T = Wk @ x^T (weights from LDS), write over the scratch ----
#pragma unroll 1
    for (int mtd = 0; mtd < 4; mtd++) {
        const bf16* wrow = WkL + (mtd * 16 + l15) * 96;
        v8bf wk3[3];
#pragma unroll
        for (int kt = 0; kt < 3; kt++)
            wk3[kt] = *(const v8bf*)(wrow + kt * 32 + quad * 8);
        float4 bk4 = *(const float4*)(bkL + mtd * 16 + quad * 4);
#pragma unroll
        for (int ntr = 0; ntr < 2; ntr++) {
            v4f acc = {0.f, 0.f, 0.f, 0.f};
#pragma unroll
            for (int kt = 0; kt < 3; kt++)
                acc = __builtin_amdgcn_mfma_f32_16x16x32_bf16(wk3[kt], xa[ntr][kt], acc, 0, 0, 0);
            int keyb = wave * 32 + ntr * 16 + l15;
            v4bf o;
            o[0] = (bf16)(acc[0] + bk4.x);
            o[1] = (bf16)(acc[1] + bk4.y);
            o[2] = (bf16)(acc[2] + bk4.z);
            o[3] = (bf16)(acc[3] + bk4.w);
            *(v4bf*)(Kb + keyb * 128 +
                     ((((mtd * 2 + (quad >> 1)) ^ (keyb & 7)) << 4) | ((quad & 1) << 3))) = o;
        }
    }
    __syncthreads();

    // ---- Phase B: S^T = K @ Q^T, exp2, weighted accumulate with vsum ----
    float osum[2] = {0.f, 0.f};
    float lsum[2] = {0.f, 0.f};
#pragma unroll 2
    for (int t = 0; t < 16; t++) {
        v8bf kf[2][2];
#pragma unroll
        for (int mtk = 0; mtk < 2; mtk++)
#pragma unroll
            for (int kt = 0; kt < 2; kt++) {
                int key = t * 32 + mtk * 16 + l15;
                kf[mtk][kt] = *(const v8bf*)(Kb + key * 128 + (((kt * 4 + quad) ^ (key & 7)) << 4));
            }
        v4f vs[2];
#pragma unroll
        for (int mtk = 0; mtk < 2; mtk++)
            vs[mtk] = *(const v4f*)(vsum + t * 32 + mtk * 16 + quad * 4);
#pragma unroll
        for (int mtk = 0; mtk < 2; mtk++) {
#pragma unroll
            for (int nt = 0; nt < 2; nt++) {
                v4f acc = {0.f, 0.f, 0.f, 0.f};
                acc = __builtin_amdgcn_mfma_f32_16x16x32_bf16(kf[mtk][0], qf[nt][0], acc, 0, 0, 0);
                acc = __builtin_amdgcn_mfma_f32_16x16x32_bf16(kf[mtk][1], qf[nt][1], acc, 0, 0, 0);
                float p0 = __builtin_amdgcn_exp2f(acc[0]);
                float p1 = __builtin_amdgcn_exp2f(acc[1]);
                float p2 = __builtin_amdgcn_exp2f(acc[2]);
                float p3 = __builtin_amdgcn_exp2f(acc[3]);
                lsum[nt] += (p0 + p1) + (p2 + p3);
                osum[nt] += ((p0 * vs[mtk][0] + p1 * vs[mtk][1]) +
                             (p2 * vs[mtk][2] + p3 * vs[mtk][3]));
            }
        }
    }

    // ---- epilogue: reduce over key-quads, out = osum/lsum ----
#pragma unroll
    for (int nt = 0; nt < 2; nt++) {
        float lv = lsum[nt];
        lv += __shfl_xor(lv, 16);
        lv += __shfl_xor(lv, 32);
        float ov = osum[nt];
        ov += __shfl_xor(ov, 16);
        ov += __shfl_xor(ov, 32);
        if (quad == 0) out[rowbase + nt * 16 + l15] = ov / lv;
    }
}

extern "C" void kernel_launch(void* const* d_in, const int* in_sizes, int n_in,
                              void* d_out, int out_size, void* d_ws, size_t ws_size,
                              hipStream_t stream) {
    const float* power = (const float*)d_in[0];
    const int*   ele_i = (const int*)d_in[1];
    // d_in[2] = range_indices: unused by the reference (positional reshape)
    const int*   azi_i = (const int*)d_in[3];
    const float* ele_t = (const float*)d_in[4];
    const float* azi_t = (const float*)d_in[5];
    const float* Wq = (const float*)d_in[6];
    const float* bq = (const float*)d_in[7];
    const float* Wk = (const float*)d_in[8];
    const float* bk = (const float*)d_in[9];
    const float* Wv = (const float*)d_in[10];
    const float* bv = (const float*)d_in[11];
    float* out = (float*)d_out;

    // Kb 64K + vsum 2K + wvs 512B + WqL 12K + WkL 12K + bqL 256B + bkL 256B
    const int lds_bytes = 93184;
    (void)hipFuncSetAttribute(reinterpret_cast<const void*>(sda_kernel),
                              hipFuncAttributeMaxDynamicSharedMemorySize, lds_bytes);
    sda_kernel<<<256, 1024, lds_bytes, stream>>>(power, ele_i, azi_i, ele_t, azi_t,
                                                 Wq, bq, Wk, bk, Wv, bv, out);
}